// Round 1
// baseline (13150.377 us; speedup 1.0000x reference)
//
#include <hip/hip_runtime.h>
#include <hip/hip_bf16.h>
#include <stdint.h>

// LSTM B=64 S=1024 D=1024 H=1024, gates f,i,o,g all sigmoid.
// Phase 1: xproj = x@W + bW + bU  (bf16 MFMA GEMM, chunked by ws_size)
// Phase 2: persistent recurrent kernel, 64 WGs (one per 16 h-cols),
//          U fragments in VGPRs, flag-array device-scope barrier per step.

typedef __attribute__((ext_vector_type(8))) short short8;
typedef __attribute__((ext_vector_type(4))) float floatx4;

__device__ __forceinline__ unsigned short f2bf(float x){
  union { float f; unsigned int u; } v; v.f = x;
  unsigned int r = v.u + 0x7fffu + ((v.u >> 16) & 1u);
  return (unsigned short)(r >> 16);
}
__device__ __forceinline__ float bf2f(unsigned short b){
  union { unsigned int u; float f; } v; v.u = ((unsigned int)b) << 16; return v.f;
}
__device__ __forceinline__ float fsigmoid(float x){ return 1.0f / (1.0f + __expf(-x)); }
// overflow-safe tanh: exp->inf gives 1, exp->0 gives -1, never NaN
__device__ __forceinline__ float ftanh(float x){ return 1.0f - 2.0f / (1.0f + __expf(2.0f * x)); }

// ---- transpose [g][d][h] fp32 -> [g][h][d] bf16 (per-gate 1024x1024) ----
__global__ void k_transpose_bf16(const float* __restrict__ src, unsigned short* __restrict__ dst){
  __shared__ float tile[64][65];
  const int g  = blockIdx.z;
  const int d0 = blockIdx.x * 64;
  const int h0 = blockIdx.y * 64;
  const int t  = threadIdx.x;
  const float* s    = src + ((size_t)g << 20);
  unsigned short* o = dst + ((size_t)g << 20);
  #pragma unroll
  for (int i = 0; i < 16; i++){
    int e = i * 256 + t;
    int r = e >> 6, c = e & 63;
    tile[r][c] = s[(size_t)(d0 + r) * 1024 + (h0 + c)];
  }
  __syncthreads();
  #pragma unroll
  for (int i = 0; i < 16; i++){
    int e = i * 256 + t;
    int a = e >> 6, bb = e & 63;
    o[(size_t)(h0 + a) * 1024 + (d0 + bb)] = f2bf(tile[bb][a]);
  }
}

// ---- convert input chunk (B,S,D) fp32 -> Abuf[(sl*64+b)][d] bf16 ----
__global__ void k_convert_x(const float* __restrict__ inp, unsigned short* __restrict__ abuf, int s0){
  int idx = blockIdx.x * 256 + threadIdx.x;   // 4 floats per thread
  int e = idx * 4;
  int r = e >> 10, d = e & 1023;
  int b = r & 63, sl = r >> 6;
  floatx4 v = *(const floatx4*)(inp + ((size_t)(b * 1024 + (s0 + sl)) * 1024 + d));
  unsigned long long pk = (unsigned long long)f2bf(v[0])
                        | ((unsigned long long)f2bf(v[1]) << 16)
                        | ((unsigned long long)f2bf(v[2]) << 32)
                        | ((unsigned long long)f2bf(v[3]) << 48);
  *(unsigned long long*)(abuf + (size_t)r * 1024 + d) = pk;
}

// ---- xproj GEMM: C[M][4096] = A[M][1024] @ Bt^T + (bW+bU), bf16 out ----
// 128x128 tile, BK=64, global_load_lds(16B) staging, XOR-swizzled LDS.
__global__ void __launch_bounds__(256) k_gemm_xproj(
    const unsigned short* __restrict__ A,
    const unsigned short* __restrict__ Bt,   // Wt[4096][1024] (N-major)
    const float* __restrict__ bW,
    const float* __restrict__ bU,
    unsigned short* __restrict__ Cc)
{
  __shared__ unsigned short As[2][128][64];
  __shared__ unsigned short Bs[2][128][64];
  const int t = threadIdx.x;
  const int w = t >> 6;
  const int lane = t & 63;
  const int m0 = blockIdx.x * 128;
  const int n0 = blockIdx.y * 128;
  floatx4 acc[4][4];
  #pragma unroll
  for (int i = 0; i < 4; i++)
    #pragma unroll
    for (int j = 0; j < 4; j++)
      acc[i][j] = (floatx4){0.f, 0.f, 0.f, 0.f};

  auto stage = [&](int bufi, int kt){
    #pragma unroll
    for (int i = 0; i < 4; i++){
      int chunk = i * 256 + t;
      int r = chunk >> 3, j = chunk & 7;
      int js = j ^ (r & 7);           // pre-swizzled global source, linear LDS dest
      __builtin_amdgcn_global_load_lds(
        (const __attribute__((address_space(1))) unsigned int*)(A + (size_t)(m0 + r) * 1024 + kt * 64 + js * 8),
        (__attribute__((address_space(3))) unsigned int*)(&As[bufi][0][0] + (i * 256 + w * 64) * 8), 16, 0, 0);
    }
    #pragma unroll
    for (int i = 0; i < 4; i++){
      int chunk = i * 256 + t;
      int r = chunk >> 3, j = chunk & 7;
      int js = j ^ (r & 7);
      __builtin_amdgcn_global_load_lds(
        (const __attribute__((address_space(1))) unsigned int*)(Bt + (size_t)(n0 + r) * 1024 + kt * 64 + js * 8),
        (__attribute__((address_space(3))) unsigned int*)(&Bs[bufi][0][0] + (i * 256 + w * 64) * 8), 16, 0, 0);
    }
  };

  auto compute = [&](int bufi){
    const int mi0 = (w >> 1) * 64;
    const int ni0 = (w & 1) * 64;
    #pragma unroll
    for (int kc = 0; kc < 2; kc++){
      short8 af[4], bfr[4];
      #pragma unroll
      for (int mi = 0; mi < 4; mi++){
        int row = mi0 + mi * 16 + (lane & 15);
        int j = kc * 4 + (lane >> 4);
        af[mi] = *(const short8*)&As[bufi][row][(j ^ (row & 7)) * 8];
      }
      #pragma unroll
      for (int ni = 0; ni < 4; ni++){
        int row = ni0 + ni * 16 + (lane & 15);
        int j = kc * 4 + (lane >> 4);
        bfr[ni] = *(const short8*)&Bs[bufi][row][(j ^ (row & 7)) * 8];
      }
      #pragma unroll
      for (int mi = 0; mi < 4; mi++)
        #pragma unroll
        for (int ni = 0; ni < 4; ni++)
          acc[mi][ni] = __builtin_amdgcn_mfma_f32_16x16x32_bf16(af[mi], bfr[ni], acc[mi][ni], 0, 0, 0);
    }
  };

  stage(0, 0);
  int buf = 0;
  for (int kt = 0; kt < 16; kt++){
    __syncthreads();                 // staged buf ready (full drain)
    if (kt < 15) stage(buf ^ 1, kt + 1);
    compute(buf);
    buf ^= 1;
  }

  {
    const int mi0 = (w >> 1) * 64;
    const int ni0 = (w & 1) * 64;
    #pragma unroll
    for (int ni = 0; ni < 4; ni++){
      int col = n0 + ni0 + ni * 16 + (lane & 15);    // col = g*1024 + h
      float bias = bW[col] + bU[col];
      #pragma unroll
      for (int mi = 0; mi < 4; mi++){
        int mrow = m0 + mi0 + mi * 16 + (lane >> 4) * 4;
        #pragma unroll
        for (int r = 0; r < 4; r++)
          Cc[(size_t)(mrow + r) * 4096 + col] = f2bf(acc[mi][ni][r] + bias);
      }
    }
  }
}

// ---- persistent recurrent kernel: 64 WGs, WG owns h-cols [wg*16, wg*16+16) ----
__global__ void __launch_bounds__(256, 1) k_lstm_rec(
    const unsigned short* __restrict__ xp,   // [SC*64][4096] bf16 (chunk)
    const unsigned short* __restrict__ Ut,   // [4096][1024] bf16
    unsigned short* hb,                      // [2][64][1024] bf16 double buffer
    float* cstate,                           // [64][1024]
    float* __restrict__ out,                 // (B,S,H) fp32
    float* __restrict__ hlast,
    float* __restrict__ clast,
    int* flags,                              // 64 flags, stride 32 ints
    int s_base, int SC)
{
  const int t = threadIdx.x;
  const int w = t >> 6;
  const int lane = t & 63;
  const int wg = blockIdx.x;
  const int c0 = wg * 16;
  __shared__ float part[4][64][64];   // 64KB: per-wave K-partial sums [wave][m][n]

  // Preload U fragments: wave w owns K-quarter [w*256, w*256+256).
  // B-operand layout (16x16x32): lane holds B[k=(l>>4)*8+j][n=l&15] -> Ut row = gatecol, contiguous k.
  short8 bfrag[4][8];
  #pragma unroll
  for (int ni = 0; ni < 4; ni++){
    const unsigned short* bp = Ut + (size_t)(ni * 1024 + c0 + (lane & 15)) * 1024 + w * 256 + (lane >> 4) * 8;
    #pragma unroll
    for (int kc = 0; kc < 8; kc++)
      bfrag[ni][kc] = *(const short8*)(bp + kc * 32);
  }

  const int b = t >> 2;            // batch owned in epilogue
  const int ci0 = (t & 3) * 4;     // 4 h-cols owned
  floatx4 c;
  if (s_base == 0) c = (floatx4){0.f, 0.f, 0.f, 0.f};
  else             c = *(const floatx4*)&cstate[(size_t)b * 1024 + c0 + ci0];

  int bail = 20000000;             // bounded spin: deadlock -> terminate (wrong), not hang

  for (int sl = 0; sl < SC; sl++){
    const int s = s_base + sl;
    const int p = s & 1;
    if (sl > 0){
      if (w == 0){
        while (__hip_atomic_load(&flags[lane * 32], __ATOMIC_RELAXED, __HIP_MEMORY_SCOPE_AGENT) < s){
          __builtin_amdgcn_s_sleep(2);
          if (--bail < 0) break;
        }
      }
      __syncthreads();
      __builtin_amdgcn_fence(__ATOMIC_ACQUIRE, "agent");   // see fresh h across XCDs
    }

    floatx4 acc[4][4];
    #pragma unroll
    for (int i = 0; i < 4; i++)
      #pragma unroll
      for (int j = 0; j < 4; j++)
        acc[i][j] = (floatx4){0.f, 0.f, 0.f, 0.f};

    // A-operand: h_prev[batch][k], lane holds A[m=l&15][k=(l>>4)*8+j]
    const unsigned short* hbp = hb + (size_t)p * 65536;
    #pragma unroll
    for (int kc = 0; kc < 8; kc++){
      short8 af[4];
      #pragma unroll
      for (int mi = 0; mi < 4; mi++){
        int row = mi * 16 + (lane & 15);
        af[mi] = *(const short8*)(hbp + (size_t)row * 1024 + w * 256 + kc * 32 + (lane >> 4) * 8);
      }
      #pragma unroll
      for (int mi = 0; mi < 4; mi++)
        #pragma unroll
        for (int ni = 0; ni < 4; ni++)
          acc[mi][ni] = __builtin_amdgcn_mfma_f32_16x16x32_bf16(af[mi], bfrag[ni][kc], acc[mi][ni], 0, 0, 0);
    }

    // publish K-partials: C layout col=l&15, row=(l>>4)*4+reg
    #pragma unroll
    for (int mi = 0; mi < 4; mi++)
      #pragma unroll
      for (int ni = 0; ni < 4; ni++)
        #pragma unroll
        for (int r = 0; r < 4; r++)
          part[w][mi * 16 + (lane >> 4) * 4 + r][ni * 16 + (lane & 15)] = acc[mi][ni][r];

    __syncthreads();

    floatx4 g4[4];
    #pragma unroll
    for (int g = 0; g < 4; g++){
      floatx4 ssum = *(const floatx4*)&part[0][b][g * 16 + ci0];
      #pragma unroll
      for (int w2 = 1; w2 < 4; w2++)
        ssum += *(const floatx4*)&part[w2][b][g * 16 + ci0];
      unsigned long long xv = *(const unsigned long long*)(xp + ((size_t)(sl * 64 + b)) * 4096 + g * 1024 + c0 + ci0);
      ssum[0] += bf2f((unsigned short)xv);
      ssum[1] += bf2f((unsigned short)(xv >> 16));
      ssum[2] += bf2f((unsigned short)(xv >> 32));
      ssum[3] += bf2f((unsigned short)(xv >> 48));
      g4[g] = ssum;
    }

    float hout[4];
    #pragma unroll
    for (int j = 0; j < 4; j++){
      float fv = fsigmoid(g4[0][j]);
      float iv = fsigmoid(g4[1][j]);
      float ov = fsigmoid(g4[2][j]);
      float gv = fsigmoid(g4[3][j]);     // reference uses sigmoid for g, not tanh
      float cv = fv * c[j] + iv * gv;
      c[j] = cv;
      hout[j] = ov * ftanh(cv);
    }

    *(floatx4*)&out[((size_t)b * 1024 + s) * 1024 + c0 + ci0] = (floatx4){hout[0], hout[1], hout[2], hout[3]};

    unsigned long long hpk = (unsigned long long)f2bf(hout[0])
                           | ((unsigned long long)f2bf(hout[1]) << 16)
                           | ((unsigned long long)f2bf(hout[2]) << 32)
                           | ((unsigned long long)f2bf(hout[3]) << 48);
    __hip_atomic_store((unsigned long long*)(hb + (size_t)(p ^ 1) * 65536 + (size_t)b * 1024 + c0 + ci0),
                       hpk, __ATOMIC_RELAXED, __HIP_MEMORY_SCOPE_AGENT);

    if (s == 1023){
      *(floatx4*)&hlast[(size_t)b * 1024 + c0 + ci0] = (floatx4){hout[0], hout[1], hout[2], hout[3]};
      *(floatx4*)&clast[(size_t)b * 1024 + c0 + ci0] = c;
    }

    __syncthreads();   // all h stores drained (syncthreads implies vmcnt drain)
    if (t == 0){
      __builtin_amdgcn_fence(__ATOMIC_RELEASE, "agent");
      __hip_atomic_store(&flags[wg * 32], s + 1, __ATOMIC_RELAXED, __HIP_MEMORY_SCOPE_AGENT);
    }
  }

  *(floatx4*)&cstate[(size_t)b * 1024 + c0 + ci0] = c;
}

extern "C" void kernel_launch(void* const* d_in, const int* in_sizes, int n_in,
                              void* d_out, int out_size, void* d_ws, size_t ws_size,
                              hipStream_t stream)
{
  (void)in_sizes; (void)n_in; (void)out_size;
  const float* input_emb = (const float*)d_in[0];
  const float* W   = (const float*)d_in[1];
  const float* bWp = (const float*)d_in[2];
  const float* U   = (const float*)d_in[3];
  const float* bUp = (const float*)d_in[4];
  float* out   = (float*)d_out;
  float* hlast = out + (size_t)64 * 1024 * 1024;
  float* clast = hlast + 64 * 1024;

  char* base = (char*)d_ws;
  unsigned short* Wt = (unsigned short*)base;  base += 8388608;   // [4096][1024] bf16
  unsigned short* Ut = (unsigned short*)base;  base += 8388608;   // [4096][1024] bf16
  unsigned short* hb = (unsigned short*)base;  base += 262144;    // [2][64][1024] bf16
  float* cstate      = (float*)base;           base += 262144;    // [64][1024] f32
  int* flags         = (int*)base;             base += 8192;      // 64 x 128B
  size_t fixed = (size_t)(base - (char*)d_ws);
  size_t avail = ws_size > fixed ? ws_size - fixed : 0;
  int SC = 1024;                                // sequence chunk (adapt to ws)
  while (SC > 8 && (size_t)SC * 655360ull > avail) SC >>= 1;
  unsigned short* Abuf = (unsigned short*)base; base += (size_t)SC * 131072;  // [SC*64][1024] bf16
  unsigned short* xp   = (unsigned short*)base;                               // [SC*64][4096] bf16

  hipMemsetAsync(flags, 0, 8192, stream);
  hipMemsetAsync(hb, 0, 131072, stream);        // h0 = 0 (parity-0 buffer)

  k_transpose_bf16<<<dim3(16, 16, 4), 256, 0, stream>>>(W, Wt);
  k_transpose_bf16<<<dim3(16, 16, 4), 256, 0, stream>>>(U, Ut);

  int nch = 1024 / SC;
  for (int cc = 0; cc < nch; cc++){
    int s0 = cc * SC;
    k_convert_x<<<SC * 64, 256, 0, stream>>>(input_emb, Abuf, s0);
    k_gemm_xproj<<<dim3(SC / 2, 32), 256, 0, stream>>>(Abuf, Wt, bWp, bUp, xp);
    k_lstm_rec<<<64, 256, 0, stream>>>(xp, Ut, hb, cstate, out, hlast, clast, flags, s0, SC);
  }
}